// Round 14
// baseline (63.121 us; speedup 1.0000x reference)
//
#include <hip/hip_runtime.h>

#define EPS 1e-8f

// Shapes fixed per reference: x [B=8, N=8192, D=512] fp32, scalar fp32 out.
#define B_DIM 8
#define N_DIM 8192
#define D_DIM 512
#define CHUNKS 256   // K1 grid = B*CHUNKS = 2048 blocks (8/CU, 32 waves/CU)
#define FIX_SCALE 1099511627776.0   // 2^40 fixed-point scale for deterministic sum
#define ACC_N (B_DIM * D_DIM)       // 4096 fixed-point accumulators

typedef float fx4 __attribute__((ext_vector_type(4)));

// K1: 256 threads (4 waves). Each wave: 8 rows, 4 rows/iteration, register
// double-buffer. Lane l owns d-slice [8l,8l+8). Block 0 zeroes acc2+ticket
// (consumed by K2, next kernel -> stream order is sufficient).
__global__ __launch_bounds__(256) void k1_partial(const float* __restrict__ x,
                                                  float* __restrict__ partial,
                                                  unsigned long long* __restrict__ acc2) {
    if (blockIdx.x == 0) {
        for (int i = threadIdx.x; i <= ACC_N; i += 256) acc2[i] = 0ULL; // [ACC_N]=ticket
    }

    constexpr int rowsPerChunk = N_DIM / CHUNKS;   // 32
    constexpr int rowsPerWave  = rowsPerChunk / 4; // 8
    constexpr int ITERS        = rowsPerWave / 4;  // 2

    const int blk   = blockIdx.x;
    const int b     = blk >> 8;            // / CHUNKS
    const int chunk = blk & (CHUNKS - 1);
    const int wave  = threadIdx.x >> 6;    // 0..3
    const int lane  = threadIdx.x & 63;

    const long long rowStart = (long long)b * N_DIM
                             + (long long)chunk * rowsPerChunk
                             + (long long)wave * rowsPerWave;

    float accv[8];
    #pragma unroll
    for (int k = 0; k < 8; ++k) accv[k] = 0.0f;

    const float* base = x + rowStart * D_DIM + lane * 8;

    fx4 v[2][4][2];

    #pragma unroll
    for (int i = 0; i < 4; ++i) {
        v[0][i][0] = *(const fx4*)(base + i * D_DIM);
        v[0][i][1] = *(const fx4*)(base + i * D_DIM + 4);
    }
    base += 4 * D_DIM;

    #pragma unroll
    for (int it = 0; it < ITERS; ++it) {
        const int cur = it & 1;
        const int nxt = cur ^ 1;

        if (it < ITERS - 1) {
            #pragma unroll
            for (int i = 0; i < 4; ++i) {
                v[nxt][i][0] = *(const fx4*)(base + i * D_DIM);
                v[nxt][i][1] = *(const fx4*)(base + i * D_DIM + 4);
            }
            base += 4 * D_DIM;
        }

        float ss[4];
        #pragma unroll
        for (int i = 0; i < 4; ++i) {
            ss[i] = v[cur][i][0].x*v[cur][i][0].x + v[cur][i][0].y*v[cur][i][0].y
                  + v[cur][i][0].z*v[cur][i][0].z + v[cur][i][0].w*v[cur][i][0].w
                  + v[cur][i][1].x*v[cur][i][1].x + v[cur][i][1].y*v[cur][i][1].y
                  + v[cur][i][1].z*v[cur][i][1].z + v[cur][i][1].w*v[cur][i][1].w;
        }

        #pragma unroll
        for (int off = 1; off < 64; off <<= 1) {
            #pragma unroll
            for (int i = 0; i < 4; ++i) ss[i] += __shfl_xor(ss[i], off);
        }

        #pragma unroll
        for (int i = 0; i < 4; ++i) {
            const float inv = 1.0f / fmaxf(sqrtf(ss[i]), EPS);
            accv[0] += v[cur][i][0].x * inv;
            accv[1] += v[cur][i][0].y * inv;
            accv[2] += v[cur][i][0].z * inv;
            accv[3] += v[cur][i][0].w * inv;
            accv[4] += v[cur][i][1].x * inv;
            accv[5] += v[cur][i][1].y * inv;
            accv[6] += v[cur][i][1].z * inv;
            accv[7] += v[cur][i][1].w * inv;
        }
    }

    __shared__ float lds[4][D_DIM];
    float* dst = &lds[wave][lane * 8];
    #pragma unroll
    for (int k = 0; k < 8; ++k) dst[k] = accv[k];
    __syncthreads();

    for (int d = threadIdx.x; d < D_DIM; d += 256) {
        float s = lds[0][d] + lds[1][d] + lds[2][d] + lds[3][d];
        partial[(long long)blk * D_DIM + d] = s;
    }
}

// K2 (single epilogue kernel): 256 blocks = (b, t, dg): b<8 batches, t<8
// chunk-supergroups (32 chunks), dg<4 d-slices (128 d's). 512 threads:
// q = tid>>5 (0..15), dq = tid&31 (d-quad). Thread sums chunks 32t+q and
// 32t+16+q at its fx4; LDS tree 16->1; 32 threads add the folded slice into
// acc2[b][d] as fixed-point u64 (8-way contention, order-independent =
// deterministic). Ticket-255 block squares/reduces acc2 -> scalar.
__global__ __launch_bounds__(512) void k2_fold(const float* __restrict__ partial,
                                               unsigned long long* __restrict__ acc2,
                                               float* __restrict__ out) {
    const int blk = blockIdx.x;
    const int b   = blk >> 5;          // /32
    const int t   = (blk >> 2) & 7;
    const int dg  = blk & 3;
    const int q   = threadIdx.x >> 5;  // 0..15
    const int dq  = threadIdx.x & 31;  // 0..31
    const int d   = dg * 128 + dq * 4;

    const float* p = partial + (long long)b * CHUNKS * D_DIM + d;
    const long long c0 = (long long)(t * 32 + q);

    fx4 s = *(const fx4*)(p + c0 * D_DIM);
    s    += *(const fx4*)(p + (c0 + 16) * D_DIM);

    __shared__ fx4 lds[16][32];
    lds[q][dq] = s;
    __syncthreads();

    if (q < 8) lds[q][dq] += lds[q + 8][dq];
    __syncthreads();
    if (q < 4) lds[q][dq] += lds[q + 4][dq];
    __syncthreads();
    if (q < 2) lds[q][dq] += lds[q + 2][dq];
    __syncthreads();
    if (q == 0) {
        const fx4 r = lds[0][dq] + lds[1][dq];
        unsigned long long* a = acc2 + (long long)b * D_DIM + d;
        #pragma unroll
        for (int j = 0; j < 4; ++j) {
            const long long qq = (long long)((double)r[j] * FIX_SCALE);
            atomicAdd(&a[j], (unsigned long long)qq);
        }
    }
    __threadfence();
    __syncthreads();

    __shared__ unsigned int lastFlag;
    if (threadIdx.x == 0) {
        const unsigned long long tk = atomicAdd(&acc2[ACC_N], 1ULL);
        lastFlag = (tk == 255ULL) ? 1U : 0U;
    }
    __syncthreads();
    if (!lastFlag) return;

    // last block: sum of squares over all 4096 (b,d) accumulators
    double v = 0.0;
    for (int i = threadIdx.x; i < ACC_N; i += 512) {
        const unsigned long long u =
            __hip_atomic_load(&acc2[i], __ATOMIC_RELAXED, __HIP_MEMORY_SCOPE_AGENT);
        const double sv = (double)(long long)u / FIX_SCALE;
        v += sv * sv;
    }
    #pragma unroll
    for (int off = 1; off < 64; off <<= 1)
        v += __shfl_xor(v, off);

    __shared__ double wsum[8];
    if ((threadIdx.x & 63) == 0) wsum[threadIdx.x >> 6] = v;
    __syncthreads();
    if (threadIdx.x == 0) {
        double tot = 0.0;
        #pragma unroll
        for (int w = 0; w < 8; ++w) tot += wsum[w];
        out[0] = (float)(tot / ((double)N_DIM * (double)N_DIM * (double)B_DIM));
    }
}

extern "C" void kernel_launch(void* const* d_in, const int* in_sizes, int n_in,
                              void* d_out, int out_size, void* d_ws, size_t ws_size,
                              hipStream_t stream) {
    const float* x = (const float*)d_in[0];
    float* out = (float*)d_out;

    float* partial = (float*)d_ws;                                  // 8*256*512 floats = 4 MB
    unsigned long long* acc2 = (unsigned long long*)((char*)d_ws +
                               (size_t)B_DIM * CHUNKS * D_DIM * sizeof(float)); // 4096 + ticket

    k1_partial<<<dim3(B_DIM * CHUNKS), dim3(256), 0, stream>>>(x, partial, acc2);
    k2_fold<<<dim3(256), dim3(512), 0, stream>>>(partial, acc2, out);
}

// Round 15
// 31.542 us; speedup vs baseline: 2.0011x; 2.0011x over previous
//
#include <hip/hip_runtime.h>

#define EPS 1e-8f

// Shapes fixed per reference: x [B=8, N=8192, D=512] fp32, scalar fp32 out.
#define B_DIM 8
#define N_DIM 8192
#define D_DIM 512
#define CHUNKS 256   // K1 grid = B*CHUNKS = 2048 blocks (8/CU, 32 waves/CU)
#define FIX_SCALE 1099511627776.0   // 2^40 fixed-point scale for deterministic sum

typedef float fx4 __attribute__((ext_vector_type(4)));

// K1: 256 threads (4 waves). Each wave: 8 rows, 4 rows/iteration, register
// double-buffer. Lane l owns d-slice [8l,8l+8). Block 0 zeroes acc/ticket
// (consumed by K2, next kernel -> stream order is sufficient).
__global__ __launch_bounds__(256) void k1_partial(const float* __restrict__ x,
                                                  float* __restrict__ partial,
                                                  unsigned long long* __restrict__ ctl) {
    if (blockIdx.x == 0 && threadIdx.x < 2) ctl[threadIdx.x] = 0ULL;

    constexpr int rowsPerChunk = N_DIM / CHUNKS;   // 32
    constexpr int rowsPerWave  = rowsPerChunk / 4; // 8
    constexpr int ITERS        = rowsPerWave / 4;  // 2

    const int blk   = blockIdx.x;
    const int b     = blk >> 8;            // / CHUNKS
    const int chunk = blk & (CHUNKS - 1);
    const int wave  = threadIdx.x >> 6;    // 0..3
    const int lane  = threadIdx.x & 63;

    const long long rowStart = (long long)b * N_DIM
                             + (long long)chunk * rowsPerChunk
                             + (long long)wave * rowsPerWave;

    float accv[8];
    #pragma unroll
    for (int k = 0; k < 8; ++k) accv[k] = 0.0f;

    const float* base = x + rowStart * D_DIM + lane * 8;

    fx4 v[2][4][2];

    #pragma unroll
    for (int i = 0; i < 4; ++i) {
        v[0][i][0] = *(const fx4*)(base + i * D_DIM);
        v[0][i][1] = *(const fx4*)(base + i * D_DIM + 4);
    }
    base += 4 * D_DIM;

    #pragma unroll
    for (int it = 0; it < ITERS; ++it) {
        const int cur = it & 1;
        const int nxt = cur ^ 1;

        if (it < ITERS - 1) {
            #pragma unroll
            for (int i = 0; i < 4; ++i) {
                v[nxt][i][0] = *(const fx4*)(base + i * D_DIM);
                v[nxt][i][1] = *(const fx4*)(base + i * D_DIM + 4);
            }
            base += 4 * D_DIM;
        }

        float ss[4];
        #pragma unroll
        for (int i = 0; i < 4; ++i) {
            ss[i] = v[cur][i][0].x*v[cur][i][0].x + v[cur][i][0].y*v[cur][i][0].y
                  + v[cur][i][0].z*v[cur][i][0].z + v[cur][i][0].w*v[cur][i][0].w
                  + v[cur][i][1].x*v[cur][i][1].x + v[cur][i][1].y*v[cur][i][1].y
                  + v[cur][i][1].z*v[cur][i][1].z + v[cur][i][1].w*v[cur][i][1].w;
        }

        #pragma unroll
        for (int off = 1; off < 64; off <<= 1) {
            #pragma unroll
            for (int i = 0; i < 4; ++i) ss[i] += __shfl_xor(ss[i], off);
        }

        #pragma unroll
        for (int i = 0; i < 4; ++i) {
            const float inv = 1.0f / fmaxf(sqrtf(ss[i]), EPS);
            accv[0] += v[cur][i][0].x * inv;
            accv[1] += v[cur][i][0].y * inv;
            accv[2] += v[cur][i][0].z * inv;
            accv[3] += v[cur][i][0].w * inv;
            accv[4] += v[cur][i][1].x * inv;
            accv[5] += v[cur][i][1].y * inv;
            accv[6] += v[cur][i][1].z * inv;
            accv[7] += v[cur][i][1].w * inv;
        }
    }

    __shared__ float lds[4][D_DIM];
    float* dst = &lds[wave][lane * 8];
    #pragma unroll
    for (int k = 0; k < 8; ++k) dst[k] = accv[k];
    __syncthreads();

    for (int d = threadIdx.x; d < D_DIM; d += 256) {
        float s = lds[0][d] + lds[1][d] + lds[2][d] + lds[3][d];
        partial[(long long)blk * D_DIM + d] = s;
    }
}

// K2: 64 blocks = (b, g) with g = d-group of 64 d's; 1024 threads (16 waves
// -> 2x the in-flight loads of the 512-thread version; K2 is latency-bound).
// Thread (q=tid>>4 in 0..63, quad=tid&15) sums chunks 4q..4q+3 at d-quad
// g*64+quad*4 (contiguous fx4, 4-deep ILP). 3-stage LDS tree 64->1, square,
// 16-lane reduce -> block ssq. Fixed-point u64 atomic add (order-independent
// = deterministic); ticket-63 block writes the final scalar.
__global__ __launch_bounds__(1024) void k2_batch(const float* __restrict__ partial,
                                                 unsigned long long* __restrict__ acc,
                                                 unsigned long long* __restrict__ ticket,
                                                 float* __restrict__ out) {
    const int b    = blockIdx.x >> 3;
    const int g    = blockIdx.x & 7;
    const int quad = threadIdx.x & 15;   // d-quad within group
    const int q    = threadIdx.x >> 4;   // 0..63 chunk-set

    const float* p = partial + (long long)b * CHUNKS * D_DIM
                   + (long long)g * 64 + quad * 4;

    const long long cbase = (long long)q * 4;
    fx4 s0 = *(const fx4*)(p + (cbase + 0) * D_DIM);
    fx4 s1 = *(const fx4*)(p + (cbase + 1) * D_DIM);
    fx4 s2 = *(const fx4*)(p + (cbase + 2) * D_DIM);
    fx4 s3 = *(const fx4*)(p + (cbase + 3) * D_DIM);
    const fx4 s = (s0 + s1) + (s2 + s3);

    __shared__ fx4 lds[64][16];
    lds[q][quad] = s;
    __syncthreads();

    // stage 1: 64 -> 16 rows
    if (q < 16) {
        lds[q][quad] = (lds[q][quad] + lds[q + 16][quad])
                     + (lds[q + 32][quad] + lds[q + 48][quad]);
    }
    __syncthreads();
    // stage 2: 16 -> 4 rows
    if (q < 4) {
        lds[q][quad] = (lds[q][quad] + lds[q + 4][quad])
                     + (lds[q + 8][quad] + lds[q + 12][quad]);
    }
    __syncthreads();
    // stage 3: 4 -> 1, then square + 16-lane reduce (threads 0..15, wave 0)
    if (threadIdx.x < 16) {
        const fx4 t = (lds[0][quad] + lds[1][quad])
                    + (lds[2][quad] + lds[3][quad]);
        float v = t.x*t.x + t.y*t.y + t.z*t.z + t.w*t.w;
        #pragma unroll
        for (int off = 1; off < 16; off <<= 1) v += __shfl_xor(v, off);

        if (threadIdx.x == 0) {
            const long long q64 = (long long)((double)v * FIX_SCALE);
            atomicAdd(acc, (unsigned long long)q64);
            __threadfence();
            const unsigned long long t63 = atomicAdd(ticket, 1ULL);
            if (t63 == (B_DIM * 8 - 1)) {
                const unsigned long long totu = atomicAdd(acc, 0ULL);
                const double tot_d = (double)(long long)totu / FIX_SCALE;
                out[0] = (float)(tot_d / ((double)N_DIM * (double)N_DIM * (double)B_DIM));
            }
        }
    }
}

extern "C" void kernel_launch(void* const* d_in, const int* in_sizes, int n_in,
                              void* d_out, int out_size, void* d_ws, size_t ws_size,
                              hipStream_t stream) {
    const float* x = (const float*)d_in[0];
    float* out = (float*)d_out;

    float* partial = (float*)d_ws;                                  // 8*256*512 floats = 4 MB
    unsigned long long* ctl = (unsigned long long*)((char*)d_ws +
                              (size_t)B_DIM * CHUNKS * D_DIM * sizeof(float));

    k1_partial<<<dim3(B_DIM * CHUNKS), dim3(256), 0, stream>>>(x, partial, ctl);
    k2_batch<<<dim3(B_DIM * 8), dim3(1024), 0, stream>>>(partial, ctl + 0, ctl + 1, out);
}